// Round 18
// baseline (88.625 us; speedup 1.0000x reference)
//
#include <hip/hip_runtime.h>

#define NB 32
#define CC 64
#define CS 32      // score cols: 0..15 alpha(x1), 16..31 phi(x2)
#define TT 300
#define VV 25
#define HH 16
#define TPOUT 150
#define KH 4       // kernel//2
#define TC 4       // timesteps per k1 block

#define TPC 25     // selected rows per k2 chunk
#define NCHUNK 6
#define ROWS_MAX 57
#define SLV 68     // k2 value-band LDS leading dim (u16)
#define SLS 36     // k2 score-band LDS leading dim (f32)

#define ALD 72     // sA row stride in u16 (144 B, 16B-aligned; b128 reads 2-way free)
#define FLD 100    // sF row stride in f32

typedef __attribute__((ext_vector_type(4))) float f32x4;
typedef __attribute__((ext_vector_type(8))) short bf16x8;

static __device__ __forceinline__ unsigned short f2bf(float f) {
    unsigned u = __float_as_uint(f);
    unsigned r = (u + 0x7FFFu + ((u >> 16) & 1u)) >> 16;   // RNE
    return (unsigned short)r;
}
static __device__ __forceinline__ float bf2f(unsigned short h) {
    return __uint_as_float(((unsigned)h) << 16);
}

// ------- Kernel 0: Wext = [W | W@aT | W@pT] -> bf16 h/l, FRAGMENT-MAJOR -----
// Layout: Wfm[((k>>3)*96 + n)*8 + (k&7)] so a lane's B-fragment is one 16 B load.
// Also zeroes ssum in-kernel (separate memset dispatch cost ~39 us in r14).
__global__ __launch_bounds__(256) void k0_prep(const float* __restrict__ W,
                                               const float* __restrict__ alpha,
                                               const float* __restrict__ phi,
                                               unsigned short* __restrict__ Wh,
                                               unsigned short* __restrict__ Wl,
                                               float* __restrict__ ssum) {
    __shared__ float sW[64][64];
    __shared__ float sA[32][64];   // rows 0..15 alpha, 16..31 phi
    __shared__ float sWe[64][96];
    const int tid = threadIdx.x;
    for (int i = tid; i < 1024; i += 256)
        reinterpret_cast<float4*>(&sW[0][0])[i] = reinterpret_cast<const float4*>(W)[i];
    for (int i = tid; i < 512; i += 256) {
        float4 v = (i < 256) ? reinterpret_cast<const float4*>(alpha)[i]
                             : reinterpret_cast<const float4*>(phi)[i - 256];
        reinterpret_cast<float4*>(&sA[0][0])[i] = v;
    }
    for (int i = tid; i < 12800; i += 256)            // zero ssum (800*64 f)
        reinterpret_cast<float4*>(ssum)[i] = (float4){0.f, 0.f, 0.f, 0.f};
    __syncthreads();
    for (int i = tid; i < 1024; i += 256) {           // copy W -> cols 0..63
        int ci = i >> 4, q = i & 15;
        *reinterpret_cast<float4*>(&sWe[ci][4 * q]) =
            reinterpret_cast<const float4*>(&sW[ci][0])[q];
    }
    for (int i = tid; i < 2048; i += 256) {           // dots -> cols 64..95
        int ci = i >> 5, j = i & 31;
        const float4* a = reinterpret_cast<const float4*>(&sW[ci][0]);
        const float4* b = reinterpret_cast<const float4*>(&sA[j][0]);
        float acc = 0.f;
#pragma unroll
        for (int q = 0; q < 16; ++q) {
            float4 u = a[q], w = b[q];
            acc += u.x * w.x + u.y * w.y + u.z * w.z + u.w * w.w;
        }
        sWe[ci][64 + j] = acc;
    }
    __syncthreads();
    for (int i = tid; i < 6144; i += 256) {
        int k = i / 96, c = i - 96 * k;
        float f = sWe[k][c];
        unsigned short h = f2bf(f);
        int off = (((k >> 3) * 96) + c) * 8 + (k & 7);
        Wh[off] = h;
        Wl[off] = f2bf(f - bf2f(h));
    }
}

// ------- Kernel 1: xwv(bf16)/xws(f32) via bf16 MFMA + fused colsum ----------
// 256 threads / 4 waves, 2 M-tiles per wave (r9's best-measured stage):
// COALESCED stage reads (25 consecutive lanes read 400 B contiguous runs),
// uint4 fragment-major LDS writes. Epilogue from r17: accs -> sF (f32,
// barrier-separated smem reuse) -> colsum partials (one global f32 atomicAdd
// each, NO LDS atomics) -> xwv bf16, xws f32.
__global__ __launch_bounds__(256) void k1_mfma(const float* __restrict__ x,
                                               const unsigned short* __restrict__ Bh,
                                               const unsigned short* __restrict__ Bl,
                                               unsigned short* __restrict__ xwv,
                                               float* __restrict__ xws,
                                               float* __restrict__ ssum) {
    __shared__ __align__(16) char smem[40000];
    unsigned short (*sAh)[ALD] = reinterpret_cast<unsigned short(*)[ALD]>(smem);
    unsigned short (*sAl)[ALD] = reinterpret_cast<unsigned short(*)[ALD]>(smem + 18432);
    float (*sF)[FLD] = reinterpret_cast<float(*)[FLD]>(smem);   // barrier-separated reuse

    const int n  = blockIdx.y;
    const int t0 = blockIdx.x * TC;
    const int tid = threadIdx.x;

    // ---- stage A: thread (cig, tq) loads 8 ci x 4 tv, packs, writes uint4 ----
    // tq-minor: lanes 0..24 read consecutive float4 -> 400 B contiguous runs.
    if (tid < 200) {
        const int cig = tid / 25, tq = tid % 25;
        const float* xp = x + (size_t)n * CC * TT * VV + (size_t)t0 * VV + 4 * tq;
        unsigned short mh[4][8], ml[4][8];
#pragma unroll
        for (int u = 0; u < 8; ++u) {
            const int ci = cig * 8 + u;
            float4 v = *reinterpret_cast<const float4*>(&xp[(size_t)ci * TT * VV]);
            unsigned short h0 = f2bf(v.x), h1 = f2bf(v.y), h2 = f2bf(v.z), h3 = f2bf(v.w);
            mh[0][u] = h0; mh[1][u] = h1; mh[2][u] = h2; mh[3][u] = h3;
            ml[0][u] = f2bf(v.x - bf2f(h0));
            ml[1][u] = f2bf(v.y - bf2f(h1));
            ml[2][u] = f2bf(v.z - bf2f(h2));
            ml[3][u] = f2bf(v.w - bf2f(h3));
        }
#pragma unroll
        for (int i = 0; i < 4; ++i) {
            *reinterpret_cast<uint4*>(&sAh[4 * tq + i][cig * 8]) =
                *reinterpret_cast<const uint4*>(&mh[i][0]);
            *reinterpret_cast<uint4*>(&sAl[4 * tq + i][cig * 8]) =
                *reinterpret_cast<const uint4*>(&ml[i][0]);
        }
    }
    __syncthreads();

    const int w    = tid >> 6;        // wave 0..3, M-tiles 2w, 2w+1
    const int lane = tid & 63;
    const int lm   = lane & 15;
    const int g    = lane >> 4;

    f32x4 acc[2][6];
#pragma unroll
    for (int a = 0; a < 2; ++a)
#pragma unroll
        for (int b = 0; b < 6; ++b) acc[a][b] = (f32x4){0.f, 0.f, 0.f, 0.f};

#pragma unroll
    for (int kh = 0; kh < 2; ++kh) {
        const int kb = kh * 32 + g * 8;
        const int kc = kb >> 3;
        const int mc0 = (2 * w + 0) * 16 + lm;
        const int mc1 = (2 * w + 1) * 16 + lm;
        bf16x8 ah0 = *reinterpret_cast<const bf16x8*>(&sAh[mc0][kb]);
        bf16x8 ah1 = *reinterpret_cast<const bf16x8*>(&sAh[mc1][kb]);
        bf16x8 al0 = *reinterpret_cast<const bf16x8*>(&sAl[mc0][kb]);
        bf16x8 al1 = *reinterpret_cast<const bf16x8*>(&sAl[mc1][kb]);
#pragma unroll
        for (int nt = 0; nt < 6; ++nt) {
            const int nc = nt * 16 + lm;
            bf16x8 bh = *reinterpret_cast<const bf16x8*>(&Bh[(size_t)(kc * 96 + nc) * 8]);
            acc[0][nt] = __builtin_amdgcn_mfma_f32_16x16x32_bf16(ah0, bh, acc[0][nt], 0, 0, 0);
            acc[1][nt] = __builtin_amdgcn_mfma_f32_16x16x32_bf16(ah1, bh, acc[1][nt], 0, 0, 0);
            if (nt >= 4) {   // score cols: h*l + l*h correction passes
                bf16x8 bl = *reinterpret_cast<const bf16x8*>(&Bl[(size_t)(kc * 96 + nc) * 8]);
                acc[0][nt] = __builtin_amdgcn_mfma_f32_16x16x32_bf16(ah0, bl, acc[0][nt], 0, 0, 0);
                acc[1][nt] = __builtin_amdgcn_mfma_f32_16x16x32_bf16(ah1, bl, acc[1][nt], 0, 0, 0);
                acc[0][nt] = __builtin_amdgcn_mfma_f32_16x16x32_bf16(al0, bh, acc[0][nt], 0, 0, 0);
                acc[1][nt] = __builtin_amdgcn_mfma_f32_16x16x32_bf16(al1, bh, acc[1][nt], 0, 0, 0);
            }
        }
    }
    __syncthreads();   // sA dead; reuse as sF

    // ---- stage accs to LDS f32 (row = tv, col = 0..95) ----
#pragma unroll
    for (int mti = 0; mti < 2; ++mti) {
#pragma unroll
        for (int j = 0; j < 4; ++j) {
            const int row = (2 * w + mti) * 16 + g * 4 + j;
            if (row < 100) {
#pragma unroll
                for (int nt = 0; nt < 6; ++nt)
                    sF[row][nt * 16 + lm] = acc[mti][nt][j];
            }
        }
    }
    __syncthreads();

    // ---- column partials -> ssum (f32 exact, pre-quantization) ----
    for (int i = tid; i < 1600; i += 256) {
        const int vv = i >> 6, c = i & 63;
        float s = sF[vv][c] + sF[vv + 25][c] + sF[vv + 50][c] + sF[vv + 75][c];
        atomicAdd(&ssum[((size_t)n * VV + vv) * CC + c], s);
    }
    // ---- xwv stores: bf16, 128 B contiguous per row ----
    for (int i = tid; i < 1600; i += 256) {
        const int row = i >> 4, q = i & 15;
        const int tloc = row / 25, vv = row - 25 * tloc;
        size_t dst = (((size_t)n * VV + vv) * TT + (t0 + tloc)) * CC + 4 * q;
        float4 v = *reinterpret_cast<const float4*>(&sF[row][4 * q]);
        ushort4 b = {f2bf(v.x), f2bf(v.y), f2bf(v.z), f2bf(v.w)};
        *reinterpret_cast<ushort4*>(&xwv[dst]) = b;
    }
    // ---- xws stores: f32, 128 B contiguous per row ----
    for (int i = tid; i < 800; i += 256) {
        const int row = i >> 3, q = i & 7;
        const int tloc = row / 25, vv = row - 25 * tloc;
        size_t dst = (((size_t)n * VV + vv) * TT + (t0 + tloc)) * CS + 4 * q;
        *reinterpret_cast<float4*>(&xws[dst]) =
            *reinterpret_cast<const float4*>(&sF[row][64 + 4 * q]);
    }
}

// ---------------- Kernel 2: banded attention, one (chunk, r) per block -------
// Value band kept bf16 in LDS; convert at the 9-tap consume.
__global__ __launch_bounds__(256) void k2_attn(const unsigned short* __restrict__ xwv,
                                               const float* __restrict__ xws,
                                               const float* __restrict__ ssum,
                                               unsigned short* __restrict__ tmp) {
    const int ch = blockIdx.x;    // 0..5
    const int r  = blockIdx.y;    // n*25 + v

    __shared__ __align__(8)  unsigned short sxv[ROWS_MAX][SLV];  // value cols, bf16
    __shared__ __align__(16) float sxs[ROWS_MAX][SLS];           // score cols, f32
    __shared__ float sss[CC];
    __shared__ float sscore[TPC][9];
    __shared__ float scoef[TPC][10];

    const int tid = threadIdx.x;
    const int tp0 = ch * TPC;
    const int s_lo = max(0, 2 * tp0 - KH);
    const int s_hi = min(TT - 1, 2 * (tp0 + TPC - 1) + KH);
    const int rows = s_hi - s_lo + 1;

    const unsigned short* bv = xwv + ((size_t)r * TT + s_lo) * CC;
    for (int i = tid; i < rows * 16; i += 256) {
        int row = i >> 4, q = i & 15;
        *reinterpret_cast<ushort4*>(&sxv[row][4 * q]) =
            *reinterpret_cast<const ushort4*>(&bv[(size_t)row * CC + 4 * q]);
    }
    const float* bs = xws + ((size_t)r * TT + s_lo) * CS;
    for (int i = tid; i < rows * 8; i += 256) {
        int row = i >> 3, q = i & 7;
        *reinterpret_cast<float4*>(&sxs[row][4 * q]) =
            *reinterpret_cast<const float4*>(&bs[(size_t)row * CS + 4 * q]);
    }
    if (tid < CC) sss[tid] = ssum[(size_t)r * CC + tid];
    __syncthreads();

    // band scores: x1 = sxs[t][0..15], x2 = sxs[s][16..31]
    if (tid < TPC * 9) {
        int tpl = tid / 9, k = tid - tpl * 9;
        int t = 2 * (tp0 + tpl);
        int s = t - KH + k;
        float sc = 0.f;
        if (s >= 0 && s < TT) {
            const float4* x1 = reinterpret_cast<const float4*>(&sxs[t - s_lo][0]);
            const float4* x2 = reinterpret_cast<const float4*>(&sxs[s - s_lo][16]);
#pragma unroll
            for (int q = 0; q < 4; ++q) {
                float4 a = x1[q], b = x2[q];
                sc += a.x * b.x + a.y * b.y + a.z * b.z + a.w * b.w;
            }
        }
        sscore[tpl][k] = sc;
    }
    __syncthreads();

    // softmax coefficients (out-of-band zeros fold analytically)
    if (tid < TPC) {
        int tpl = tid;
        int t = 2 * (tp0 + tpl);
        float m = 0.f;
        int nb = 0;
#pragma unroll
        for (int k = 0; k < 9; ++k) {
            int s = t - KH + k;
            if (s >= 0 && s < TT) { nb++; m = fmaxf(m, sscore[tpl][k]); }
        }
        float wbg = __expf(-m);
        float Z = (float)(TT - nb) * wbg;
        float e[9];
#pragma unroll
        for (int k = 0; k < 9; ++k) {
            int s = t - KH + k;
            float ek = (s >= 0 && s < TT) ? __expf(sscore[tpl][k] - m) : 0.f;
            e[k] = ek;
            Z += ek;
        }
        float inv = 1.f / Z;
#pragma unroll
        for (int k = 0; k < 9; ++k) {
            int s = t - KH + k;
            scoef[tpl][k] = (s >= 0 && s < TT) ? (e[k] - wbg) * inv : 0.f;
        }
        scoef[tpl][9] = wbg * inv;
    }
    __syncthreads();

    // tmp[r][tp][c] = cbg*ssum[c] + sum_k coef_k * band[row][c]   (bf16 store)
    for (int i = tid; i < TPC * CC; i += 256) {
        int tpl = i >> 6, c = i & 63;
        int t = 2 * (tp0 + tpl);
        int row0 = t - KH - s_lo;
        float val = scoef[tpl][9] * sss[c];
#pragma unroll
        for (int k = 0; k < 9; ++k) {
            int row = row0 + k;
            row = min(max(row, 0), rows - 1);   // coef is 0 for invalid slots
            val += scoef[tpl][k] * bf2f(sxv[row][c]);
        }
        tmp[((size_t)r * TPOUT + (tp0 + tpl)) * CC + c] = f2bf(val);
    }
}

// ---------------- Kernel 3: tmp[n][v][tp][c] (bf16) -> out[n][c][tp][v] ------
#define TPT 5
#define TLD 68
__global__ __launch_bounds__(256) void k3_transpose(const unsigned short* __restrict__ tmp,
                                                    float* __restrict__ out) {
    __shared__ __align__(8) unsigned short tile[VV][TPT][TLD];
    const int n = blockIdx.y;
    const int tp0 = blockIdx.x * TPT;
    const int tid = threadIdx.x;

    const unsigned short* src = tmp + (size_t)n * (VV * TPOUT * CC);
    for (int i = tid; i < VV * TPT * 16; i += 256) {
        int v = i / (TPT * 16);
        int rem = i - v * (TPT * 16);
        int tpl = rem >> 4, q = rem & 15;
        *reinterpret_cast<ushort4*>(&tile[v][tpl][4 * q]) =
            *reinterpret_cast<const ushort4*>(
                &src[((size_t)v * TPOUT + tp0 + tpl) * CC + 4 * q]);
    }
    __syncthreads();
    float* dst = out + (size_t)n * (CC * TPOUT * VV);
    for (int j = tid; j < CC * TPT * VV; j += 256) {
        int c = j / (TPT * VV);
        int rem = j - c * (TPT * VV);
        int tpl = rem / VV, v = rem - tpl * VV;
        dst[(size_t)c * (TPOUT * VV) + (tp0 + tpl) * VV + v] = bf2f(tile[v][tpl][c]);
    }
}

extern "C" void kernel_launch(void* const* d_in, const int* in_sizes, int n_in,
                              void* d_out, int out_size, void* d_ws, size_t ws_size,
                              hipStream_t stream) {
    const float* x     = (const float*)d_in[0];
    const float* W     = (const float*)d_in[1];
    const float* alpha = (const float*)d_in[2];
    const float* phi   = (const float*)d_in[3];
    float* out = (float*)d_out;

    float* xws  = (float*)d_ws;                          // 800*300*32 f32
    float* ssum = xws + (size_t)800 * 300 * CS;          // 800*64 f32
    unsigned short* xwv = (unsigned short*)(ssum + (size_t)800 * 64);  // 800*300*64 u16
    unsigned short* tmp = xwv + (size_t)800 * 300 * CC;  // 800*150*64 u16
    unsigned short* Wh  = tmp + (size_t)800 * 150 * CC;  // 6144 u16
    unsigned short* Wl  = Wh + 6144;                     // 6144 u16 (~77 MB total)

    k0_prep<<<1, 256, 0, stream>>>(W, alpha, phi, Wh, Wl, ssum);
    dim3 g1(TT / TC, NB);
    k1_mfma<<<g1, 256, 0, stream>>>(x, Wh, Wl, xwv, xws, ssum);
    dim3 g2(NCHUNK, NB * VV);
    k2_attn<<<g2, 256, 0, stream>>>(xwv, xws, ssum, tmp);
    dim3 g3(TPOUT / TPT, NB);
    k3_transpose<<<g3, 256, 0, stream>>>(tmp, out);
}

// Round 19
// 82.398 us; speedup vs baseline: 1.0756x; 1.0756x over previous
//
#include <hip/hip_runtime.h>

#define NB 32
#define CC 64
#define CS 32      // score cols: 0..15 alpha(x1), 16..31 phi(x2)
#define TT 300
#define VV 25
#define HH 16
#define TPOUT 150
#define KH 4       // kernel//2
#define TC 4       // timesteps per k1 block

#define TPC 25     // selected rows per k2 chunk
#define NCHUNK 6
#define ROWS_MAX 57
#define SLV 68     // k2 value-band LDS leading dim (u16)
#define SLS 36     // k2 score-band LDS leading dim (f32)

#define ALD 72     // sA row stride in u16 (144 B, 16B-aligned; b128 reads 2-way free)
#define FLD 100    // sF row stride in f32

typedef __attribute__((ext_vector_type(4))) float f32x4;
typedef __attribute__((ext_vector_type(8))) short bf16x8;

static __device__ __forceinline__ unsigned short f2bf(float f) {
    unsigned u = __float_as_uint(f);
    unsigned r = (u + 0x7FFFu + ((u >> 16) & 1u)) >> 16;   // RNE
    return (unsigned short)r;
}
static __device__ __forceinline__ float bf2f(unsigned short h) {
    return __uint_as_float(((unsigned)h) << 16);
}

// ------- Kernel 0: Wext = [W | W@aT | W@pT] -> bf16 h/l, FRAGMENT-MAJOR -----
// Layout: Wfm[((k>>3)*96 + n)*8 + (k&7)] so a lane's B-fragment is one 16 B load.
// 64 blocks: ALL blocks zero a slice of ssum (200 KB via one CU was ~8 us of
// serial time); block 0 alone computes the 24 KB Wext tables.
__global__ __launch_bounds__(256) void k0_prep(const float* __restrict__ W,
                                               const float* __restrict__ alpha,
                                               const float* __restrict__ phi,
                                               unsigned short* __restrict__ Wh,
                                               unsigned short* __restrict__ Wl,
                                               float* __restrict__ ssum) {
    const int tid = threadIdx.x;
    // parallel ssum zeroing: 12800 float4 over 64x256 threads (single pass)
    {
        int i = blockIdx.x * 256 + tid;
        if (i < 12800)
            reinterpret_cast<float4*>(ssum)[i] = (float4){0.f, 0.f, 0.f, 0.f};
    }
    if (blockIdx.x != 0) return;

    __shared__ float sW[64][64];
    __shared__ float sA[32][64];   // rows 0..15 alpha, 16..31 phi
    __shared__ float sWe[64][96];
    for (int i = tid; i < 1024; i += 256)
        reinterpret_cast<float4*>(&sW[0][0])[i] = reinterpret_cast<const float4*>(W)[i];
    for (int i = tid; i < 512; i += 256) {
        float4 v = (i < 256) ? reinterpret_cast<const float4*>(alpha)[i]
                             : reinterpret_cast<const float4*>(phi)[i - 256];
        reinterpret_cast<float4*>(&sA[0][0])[i] = v;
    }
    __syncthreads();
    for (int i = tid; i < 1024; i += 256) {           // copy W -> cols 0..63
        int ci = i >> 4, q = i & 15;
        *reinterpret_cast<float4*>(&sWe[ci][4 * q]) =
            reinterpret_cast<const float4*>(&sW[ci][0])[q];
    }
    for (int i = tid; i < 2048; i += 256) {           // dots -> cols 64..95
        int ci = i >> 5, j = i & 31;
        const float4* a = reinterpret_cast<const float4*>(&sW[ci][0]);
        const float4* b = reinterpret_cast<const float4*>(&sA[j][0]);
        float acc = 0.f;
#pragma unroll
        for (int q = 0; q < 16; ++q) {
            float4 u = a[q], w = b[q];
            acc += u.x * w.x + u.y * w.y + u.z * w.z + u.w * w.w;
        }
        sWe[ci][64 + j] = acc;
    }
    __syncthreads();
    for (int i = tid; i < 6144; i += 256) {
        int k = i / 96, c = i - 96 * k;
        float f = sWe[k][c];
        unsigned short h = f2bf(f);
        int off = (((k >> 3) * 96) + c) * 8 + (k & 7);
        Wh[off] = h;
        Wl[off] = f2bf(f - bf2f(h));
    }
}

// ------- Kernel 1: xwv(bf16)/xws(f32) via bf16 MFMA + fused colsum ----------
// r15/r17 proven structure (best measured): 512 threads / 8 waves, one 16-row
// M-tile/wave, r-major [r][t][c] workspace. Epilogue: accs -> sF (f32,
// barrier-separated smem reuse) -> colsum partials (one global f32 atomicAdd
// each, NO LDS atomics) -> xwv bf16, xws f32.
__global__ __launch_bounds__(512) void k1_mfma(const float* __restrict__ x,
                                               const unsigned short* __restrict__ Bh,
                                               const unsigned short* __restrict__ Bl,
                                               unsigned short* __restrict__ xwv,
                                               float* __restrict__ xws,
                                               float* __restrict__ ssum) {
    __shared__ __align__(16) char smem[40000];
    unsigned short (*sAh)[ALD] = reinterpret_cast<unsigned short(*)[ALD]>(smem);
    unsigned short (*sAl)[ALD] = reinterpret_cast<unsigned short(*)[ALD]>(smem + 18432);
    float (*sF)[FLD] = reinterpret_cast<float(*)[FLD]>(smem);   // barrier-separated reuse

    const int n  = blockIdx.y;
    const int t0 = blockIdx.x * TC;
    const int tid = threadIdx.x;

    // ---- stage A: thread (tq, cig) loads 4 ci x 4 tv, packs, writes uint2 ----
    if (tid < 400) {
        const int cig = tid & 15, tq = tid >> 4;      // tq 0..24
        const float* xp = x + (size_t)n * CC * TT * VV + (size_t)t0 * VV + 4 * tq;
        unsigned short mh[4][4], ml[4][4];
#pragma unroll
        for (int u = 0; u < 4; ++u) {
            const int ci = cig * 4 + u;
            float4 v = *reinterpret_cast<const float4*>(&xp[(size_t)ci * TT * VV]);
            unsigned short h0 = f2bf(v.x), h1 = f2bf(v.y), h2 = f2bf(v.z), h3 = f2bf(v.w);
            mh[0][u] = h0; mh[1][u] = h1; mh[2][u] = h2; mh[3][u] = h3;
            ml[0][u] = f2bf(v.x - bf2f(h0));
            ml[1][u] = f2bf(v.y - bf2f(h1));
            ml[2][u] = f2bf(v.z - bf2f(h2));
            ml[3][u] = f2bf(v.w - bf2f(h3));
        }
#pragma unroll
        for (int i = 0; i < 4; ++i) {
            *reinterpret_cast<uint2*>(&sAh[4 * tq + i][cig * 4]) =
                *reinterpret_cast<const uint2*>(&mh[i][0]);
            *reinterpret_cast<uint2*>(&sAl[4 * tq + i][cig * 4]) =
                *reinterpret_cast<const uint2*>(&ml[i][0]);
        }
    }
    __syncthreads();

    const int w    = tid >> 6;        // wave = M-tile 0..7
    const int lane = tid & 63;
    const int lm   = lane & 15;
    const int g    = lane >> 4;
    const int mc   = w * 16 + lm;

    f32x4 acc[6];
#pragma unroll
    for (int b = 0; b < 6; ++b) acc[b] = (f32x4){0.f, 0.f, 0.f, 0.f};

#pragma unroll
    for (int kh = 0; kh < 2; ++kh) {
        const int kb = kh * 32 + g * 8;
        const int kc = kb >> 3;
        bf16x8 ah = *reinterpret_cast<const bf16x8*>(&sAh[mc][kb]);
        bf16x8 al = *reinterpret_cast<const bf16x8*>(&sAl[mc][kb]);
#pragma unroll
        for (int nt = 0; nt < 6; ++nt) {
            const int nc = nt * 16 + lm;
            bf16x8 bh = *reinterpret_cast<const bf16x8*>(&Bh[(size_t)(kc * 96 + nc) * 8]);
            acc[nt] = __builtin_amdgcn_mfma_f32_16x16x32_bf16(ah, bh, acc[nt], 0, 0, 0);
            if (nt >= 4) {   // score cols: h*l + l*h correction passes
                bf16x8 bl = *reinterpret_cast<const bf16x8*>(&Bl[(size_t)(kc * 96 + nc) * 8]);
                acc[nt] = __builtin_amdgcn_mfma_f32_16x16x32_bf16(ah, bl, acc[nt], 0, 0, 0);
                acc[nt] = __builtin_amdgcn_mfma_f32_16x16x32_bf16(al, bh, acc[nt], 0, 0, 0);
            }
        }
    }
    __syncthreads();   // sA dead; reuse as sF

    // ---- stage accs to LDS f32 (row = tv, col = 0..95) ----
#pragma unroll
    for (int j = 0; j < 4; ++j) {
        const int row = w * 16 + g * 4 + j;
        if (row < 100) {
#pragma unroll
            for (int nt = 0; nt < 6; ++nt)
                sF[row][nt * 16 + lm] = acc[nt][j];
        }
    }
    __syncthreads();

    // ---- column partials -> ssum (f32 exact, pre-quantization) ----
    for (int i = tid; i < 1600; i += 512) {
        const int vv = i >> 6, c = i & 63;
        float s = sF[vv][c] + sF[vv + 25][c] + sF[vv + 50][c] + sF[vv + 75][c];
        atomicAdd(&ssum[((size_t)n * VV + vv) * CC + c], s);
    }
    // ---- xwv stores: bf16, 128 B contiguous per row ----
    for (int i = tid; i < 1600; i += 512) {
        const int row = i >> 4, q = i & 15;
        const int tloc = row / 25, vv = row - 25 * tloc;
        size_t dst = (((size_t)n * VV + vv) * TT + (t0 + tloc)) * CC + 4 * q;
        float4 v = *reinterpret_cast<const float4*>(&sF[row][4 * q]);
        ushort4 b = {f2bf(v.x), f2bf(v.y), f2bf(v.z), f2bf(v.w)};
        *reinterpret_cast<ushort4*>(&xwv[dst]) = b;
    }
    // ---- xws stores: f32, 128 B contiguous per row ----
    for (int i = tid; i < 800; i += 512) {
        const int row = i >> 3, q = i & 7;
        const int tloc = row / 25, vv = row - 25 * tloc;
        size_t dst = (((size_t)n * VV + vv) * TT + (t0 + tloc)) * CS + 4 * q;
        *reinterpret_cast<float4*>(&xws[dst]) =
            *reinterpret_cast<const float4*>(&sF[row][64 + 4 * q]);
    }
}

// ---------------- Kernel 2: banded attention, one (chunk, r) per block -------
// Value band kept bf16 in LDS (halves its footprint); convert at the 9-tap
// consume. Math identical to r15.
__global__ __launch_bounds__(256) void k2_attn(const unsigned short* __restrict__ xwv,
                                               const float* __restrict__ xws,
                                               const float* __restrict__ ssum,
                                               unsigned short* __restrict__ tmp) {
    const int ch = blockIdx.x;    // 0..5
    const int r  = blockIdx.y;    // n*25 + v

    __shared__ __align__(8)  unsigned short sxv[ROWS_MAX][SLV];  // value cols, bf16
    __shared__ __align__(16) float sxs[ROWS_MAX][SLS];           // score cols, f32
    __shared__ float sss[CC];
    __shared__ float sscore[TPC][9];
    __shared__ float scoef[TPC][10];

    const int tid = threadIdx.x;
    const int tp0 = ch * TPC;
    const int s_lo = max(0, 2 * tp0 - KH);
    const int s_hi = min(TT - 1, 2 * (tp0 + TPC - 1) + KH);
    const int rows = s_hi - s_lo + 1;

    const unsigned short* bv = xwv + ((size_t)r * TT + s_lo) * CC;
    for (int i = tid; i < rows * 16; i += 256) {
        int row = i >> 4, q = i & 15;
        *reinterpret_cast<ushort4*>(&sxv[row][4 * q]) =
            *reinterpret_cast<const ushort4*>(&bv[(size_t)row * CC + 4 * q]);
    }
    const float* bs = xws + ((size_t)r * TT + s_lo) * CS;
    for (int i = tid; i < rows * 8; i += 256) {
        int row = i >> 3, q = i & 7;
        *reinterpret_cast<float4*>(&sxs[row][4 * q]) =
            *reinterpret_cast<const float4*>(&bs[(size_t)row * CS + 4 * q]);
    }
    if (tid < CC) sss[tid] = ssum[(size_t)r * CC + tid];
    __syncthreads();

    // band scores: x1 = sxs[t][0..15], x2 = sxs[s][16..31]
    if (tid < TPC * 9) {
        int tpl = tid / 9, k = tid - tpl * 9;
        int t = 2 * (tp0 + tpl);
        int s = t - KH + k;
        float sc = 0.f;
        if (s >= 0 && s < TT) {
            const float4* x1 = reinterpret_cast<const float4*>(&sxs[t - s_lo][0]);
            const float4* x2 = reinterpret_cast<const float4*>(&sxs[s - s_lo][16]);
#pragma unroll
            for (int q = 0; q < 4; ++q) {
                float4 a = x1[q], b = x2[q];
                sc += a.x * b.x + a.y * b.y + a.z * b.z + a.w * b.w;
            }
        }
        sscore[tpl][k] = sc;
    }
    __syncthreads();

    // softmax coefficients (out-of-band zeros fold analytically)
    if (tid < TPC) {
        int tpl = tid;
        int t = 2 * (tp0 + tpl);
        float m = 0.f;
        int nb = 0;
#pragma unroll
        for (int k = 0; k < 9; ++k) {
            int s = t - KH + k;
            if (s >= 0 && s < TT) { nb++; m = fmaxf(m, sscore[tpl][k]); }
        }
        float wbg = __expf(-m);
        float Z = (float)(TT - nb) * wbg;
        float e[9];
#pragma unroll
        for (int k = 0; k < 9; ++k) {
            int s = t - KH + k;
            float ek = (s >= 0 && s < TT) ? __expf(sscore[tpl][k] - m) : 0.f;
            e[k] = ek;
            Z += ek;
        }
        float inv = 1.f / Z;
#pragma unroll
        for (int k = 0; k < 9; ++k) {
            int s = t - KH + k;
            scoef[tpl][k] = (s >= 0 && s < TT) ? (e[k] - wbg) * inv : 0.f;
        }
        scoef[tpl][9] = wbg * inv;
    }
    __syncthreads();

    // tmp[r][tp][c] = cbg*ssum[c] + sum_k coef_k * band[row][c]   (bf16 store)
    for (int i = tid; i < TPC * CC; i += 256) {
        int tpl = i >> 6, c = i & 63;
        int t = 2 * (tp0 + tpl);
        int row0 = t - KH - s_lo;
        float val = scoef[tpl][9] * sss[c];
#pragma unroll
        for (int k = 0; k < 9; ++k) {
            int row = row0 + k;
            row = min(max(row, 0), rows - 1);   // coef is 0 for invalid slots
            val += scoef[tpl][k] * bf2f(sxv[row][c]);
        }
        tmp[((size_t)r * TPOUT + (tp0 + tpl)) * CC + c] = f2bf(val);
    }
}

// ---------------- Kernel 3: tmp[n][v][tp][c] (bf16) -> out[n][c][tp][v] ------
#define TPT 5
#define TLD 68
__global__ __launch_bounds__(256) void k3_transpose(const unsigned short* __restrict__ tmp,
                                                    float* __restrict__ out) {
    __shared__ __align__(8) unsigned short tile[VV][TPT][TLD];
    const int n = blockIdx.y;
    const int tp0 = blockIdx.x * TPT;
    const int tid = threadIdx.x;

    const unsigned short* src = tmp + (size_t)n * (VV * TPOUT * CC);
    for (int i = tid; i < VV * TPT * 16; i += 256) {
        int v = i / (TPT * 16);
        int rem = i - v * (TPT * 16);
        int tpl = rem >> 4, q = rem & 15;
        *reinterpret_cast<ushort4*>(&tile[v][tpl][4 * q]) =
            *reinterpret_cast<const ushort4*>(
                &src[((size_t)v * TPOUT + tp0 + tpl) * CC + 4 * q]);
    }
    __syncthreads();
    float* dst = out + (size_t)n * (CC * TPOUT * VV);
    for (int j = tid; j < CC * TPT * VV; j += 256) {
        int c = j / (TPT * VV);
        int rem = j - c * (TPT * VV);
        int tpl = rem / VV, v = rem - tpl * VV;
        dst[(size_t)c * (TPOUT * VV) + (tp0 + tpl) * VV + v] = bf2f(tile[v][tpl][c]);
    }
}

extern "C" void kernel_launch(void* const* d_in, const int* in_sizes, int n_in,
                              void* d_out, int out_size, void* d_ws, size_t ws_size,
                              hipStream_t stream) {
    const float* x     = (const float*)d_in[0];
    const float* W     = (const float*)d_in[1];
    const float* alpha = (const float*)d_in[2];
    const float* phi   = (const float*)d_in[3];
    float* out = (float*)d_out;

    float* xws  = (float*)d_ws;                          // 800*300*32 f32
    float* ssum = xws + (size_t)800 * 300 * CS;          // 800*64 f32
    unsigned short* xwv = (unsigned short*)(ssum + (size_t)800 * 64);  // 800*300*64 u16
    unsigned short* tmp = xwv + (size_t)800 * 300 * CC;  // 800*150*64 u16
    unsigned short* Wh  = tmp + (size_t)800 * 150 * CC;  // 6144 u16
    unsigned short* Wl  = Wh + 6144;                     // 6144 u16 (~77 MB total)

    k0_prep<<<64, 256, 0, stream>>>(W, alpha, phi, Wh, Wl, ssum);
    dim3 g1(TT / TC, NB);
    k1_mfma<<<g1, 512, 0, stream>>>(x, Wh, Wl, xwv, xws, ssum);
    dim3 g2(NCHUNK, NB * VV);
    k2_attn<<<g2, 256, 0, stream>>>(xwv, xws, ssum, tmp);
    dim3 g3(TPOUT / TPT, NB);
    k3_transpose<<<g3, 256, 0, stream>>>(tmp, out);
}